// Round 8
// baseline (905.199 us; speedup 1.0000x reference)
//
#include <hip/hip_runtime.h>
#include <hip/hip_bf16.h>

// GraphUpsampler: N=4096 -> M=8192 dense GCN, 3 iters, out = sigmoid(Xu@Xu.T) f32 [8192,8192].
// R13: agg64 -> agg128. R6/R10/R12 nulls match the guide's "T2/T4 null on 2-phase" quadrant:
//   2-phase kernels are barrier/stage-bound, so raise MFMA-per-barrier instead of shaving
//   reads. agg128: 128x128 tile, BK=64 (2 tiled sub-stages/stage), double-buffered LDS
//   (2x32KB -> still 2 blocks/CU), counted vmcnt 8/0, 32 MFMA per barrier-pair per wave
//   (4x R12), barrier-pair count halved. Staging = lane-linear gld16 + 8-chunk XOR involution
//   (same verified pattern as yz). reduce64 mode-1 decode updated. Else identical to R12.

#define N_NODES 4096
#define M_NODES 8192
#define DIM 128
#define SLICE_ELEMS ((size_t)M_NODES * DIM)

typedef __attribute__((ext_vector_type(4))) float f32x4;
typedef __attribute__((ext_vector_type(8))) short bf16x8;

__device__ __forceinline__ unsigned short f2bf(float f) {
  union { float f; unsigned u; } v; v.f = f;
  unsigned r = v.u + 0x7fffu + ((v.u >> 16) & 1u);
  return (unsigned short)(r >> 16);
}

__device__ __forceinline__ void gld16(unsigned short* lds, const unsigned short* g) {
  __builtin_amdgcn_global_load_lds(
      (const __attribute__((address_space(1))) unsigned int*)g,
      (__attribute__((address_space(3))) unsigned int*)lds, 16, 0, 0);
}

__device__ __forceinline__ float sigmoidf_(float x) { return 1.0f / (1.0f + __expf(-x)); }

// ---------------- cast / init kernels ----------------

__global__ void cast_x_kernel(const float* __restrict__ X, unsigned short* __restrict__ Xu,
                              unsigned short* __restrict__ XT,
                              float* __restrict__ colsumA) {
  int idx = blockIdx.x * 256 + threadIdx.x;          // N*DIM
  if (idx < N_NODES) colsumA[idx] = 0.f;             // folded memset (before cast_a)
  int i = idx >> 7, c = idx & 127;
  unsigned short b = f2bf(X[idx]);
  Xu[idx] = b;
  XT[(size_t)c * N_NODES + i] = b;                   // X^T [128][4096]
}

// both 128x128 conv weights -> W^T [out][in] bf16, one launch
__global__ void cast_wt2_kernel(const float* __restrict__ W1, const float* __restrict__ W2,
                                unsigned short* __restrict__ WT1,
                                unsigned short* __restrict__ WT2) {
  int idx = blockIdx.x * 256 + threadIdx.x;          // 2*128*128
  const float* W = idx < 16384 ? W1 : W2;
  unsigned short* WT = idx < 16384 ? WT1 : WT2;
  int j = idx & 16383;
  int k = j >> 7, c = j & 127;
  WT[c * DIM + k] = f2bf(W[j]);
}

// A f32 -> 3 blocks of stage-tiled Adj ([[A,A],[A,.]], A symmetric) + colsum(A)
__global__ void cast_a_kernel(const float* __restrict__ A, unsigned short* __restrict__ Adj,
                              float* __restrict__ colsumA) {
  int c = blockIdx.x * 256 + threadIdx.x;            // grid.x = 16
  int r0 = blockIdx.y * 128;
  int tm = r0 >> 7;
  int kc = c >> 10, st = (c & 1023) >> 5, e = c & 31;
  size_t a1 = ((size_t)(tm)      * 8 + kc)     * 131072 + (size_t)st * 4096 + e;  // (r,c)
  size_t a2 = ((size_t)(tm)      * 8 + 4 + kc) * 131072 + (size_t)st * 4096 + e;  // (r,4096+c)
  size_t a3 = ((size_t)(tm + 32) * 8 + kc)     * 131072 + (size_t)st * 4096 + e;  // (4096+r,c)
  float s = 0.f;
  for (int r = 0; r < 128; ++r) {
    float a = A[(size_t)(r0 + r) * N_NODES + c];
    unsigned short b = f2bf(a);
    Adj[a1 + r * 32] = b; Adj[a2 + r * 32] = b; Adj[a3 + r * 32] = b;
    s += a;
  }
  atomicAdd(&colsumA[c], s);
}

__global__ void init_deg_kernel(const float* __restrict__ colsumA, float* __restrict__ deg) {
  int i = blockIdx.x * 256 + threadIdx.x;            // 8192
  deg[i] = (i < N_NODES) ? 2.0f * colsumA[i] : colsumA[i - N_NODES];
}

// ---------------- conv aggregation GEMM: 128x128 tile, BK=64, split-K 8 ----------------
// C_partial[by] = Adj(stage-tiled)[128 rows x 1024 k] @ Z (ZT [128 n][8192 k]).
// Double-buffered (2x32KB LDS, 2 blocks/CU); 8 gld16/thread/stage -> counted vmcnt 8/0.
// LDS tiles [row][8 chunks of 8e]: phys chunk = logical ^ (row&7) via pre-swizzled source;
// read key xk=l15&7 (row&7==l15&7 for all fragment rows). 32 MFMA per barrier-pair per wave.

__global__ __launch_bounds__(256, 2)
void agg128_kernel(const unsigned short* __restrict__ At,
                   const unsigned short* __restrict__ BT, long ldb,
                   float* __restrict__ accBase, int kIters) {
  __shared__ __align__(16) unsigned short smem[32768];   // 2 bufs x (8192 A + 8192 B) elems
  const int t = threadIdx.x, w = t >> 6, lane = t & 63;
  const int q = lane >> 4, l15 = lane & 15;
  const int xk = l15 & 7;                            // read-side swizzle key
  const int tm = blockIdx.x;                         // 128-row tile
  const int sg0 = blockIdx.y * (kIters * 2);         // first 32-wide sub-stage
  const size_t kbase = (size_t)sg0 * 32;             // k origin for B

  auto STAGE = [&](int s, int b) {
    unsigned short* la = smem + b * 16384;
    unsigned short* lb = la + 8192;
#pragma unroll
    for (int j = 0; j < 4; ++j) {
      int ch = j * 256 + t;                          // 0..1023
      int row = ch >> 3, phys = ch & 7;
      int c = phys ^ (row & 7);
      int sg = sg0 + 2 * s + (c >> 2);
      gld16(&la[ch * 8],
            &At[((size_t)tm * 8 + (sg >> 5)) * 131072 + (size_t)(sg & 31) * 4096 +
                row * 32 + (c & 3) * 8]);
      gld16(&lb[ch * 8], &BT[(size_t)row * ldb + kbase + s * 64 + c * 8]);
    }
  };

  f32x4 acc[2][8];
#pragma unroll
  for (int a = 0; a < 2; ++a)
#pragma unroll
    for (int b = 0; b < 8; ++b) acc[a][b] = (f32x4)0.f;

  STAGE(0, 0);

  for (int s = 0; s < kIters; ++s) {
    if (s + 1 < kIters) {
      STAGE(s + 1, (s + 1) & 1);
      asm volatile("s_waitcnt vmcnt(8)" ::: "memory");   // stage s's 8 loads complete
    } else {
      asm volatile("s_waitcnt vmcnt(0)" ::: "memory");
    }
    __builtin_amdgcn_s_barrier();
    __builtin_amdgcn_sched_barrier(0);

    const unsigned short* la = smem + (s & 1) * 16384;
    const unsigned short* lb = la + 8192;
#pragma unroll
    for (int kk = 0; kk < 2; ++kk) {
      bf16x8 a0 = *(const bf16x8*)&la[(w * 32 + l15) * 64 + (((kk << 2) + q) ^ xk) * 8];
      bf16x8 a1 = *(const bf16x8*)&la[(w * 32 + 16 + l15) * 64 + (((kk << 2) + q) ^ xk) * 8];
#pragma unroll
      for (int nt = 0; nt < 8; ++nt) {
        bf16x8 b = *(const bf16x8*)&lb[(nt * 16 + l15) * 64 + (((kk << 2) + q) ^ xk) * 8];
        acc[0][nt] = __builtin_amdgcn_mfma_f32_16x16x32_bf16(a0, b, acc[0][nt], 0, 0, 0);
        acc[1][nt] = __builtin_amdgcn_mfma_f32_16x16x32_bf16(a1, b, acc[1][nt], 0, 0, 0);
      }
    }
    __builtin_amdgcn_sched_barrier(0);
    __builtin_amdgcn_s_barrier();                    // buf (s&1) free for reuse
    __builtin_amdgcn_sched_barrier(0);
  }
  // packed C per block: 128x128 = 16384 floats; 16B/lane coalesced
  // slot = w*16 + mt*8 + nt; row = tile*128 + w*32 + mt*16 + q*4 + i; col = nt*16 + l15
  float* ct = accBase + (size_t)blockIdx.y * SLICE_ELEMS + (size_t)blockIdx.x * 16384;
#pragma unroll
  for (int mt = 0; mt < 2; ++mt)
#pragma unroll
    for (int nt = 0; nt < 8; ++nt)
      *(f32x4*)&ct[((w * 16 + mt * 8 + nt) * 256) + (q * 16 + l15) * 4] = acc[mt][nt];
}

// ---------------- upsample GEMM reading W_up f32 directly ----------------
// out_partial[by] = f2bf(W_up)[64 rows x 512 k] @ X (XT [128 d][4096 k]).

__global__ __launch_bounds__(256)
void up_agg_f32(const float* __restrict__ Wup, const unsigned short* __restrict__ BT,
                float* __restrict__ accBase) {
  __shared__ __align__(16) unsigned short smem[6144];    // A 4KB + B 8KB
  unsigned short* la = smem;
  unsigned short* lb = smem + 2048;
  const int t = threadIdx.x, w = t >> 6, lane = t & 63;
  const int q = lane >> 4, l15 = lane & 15;
  const int r0 = blockIdx.x * 64;                    // output rows
  const int k0 = blockIdx.y * 512;                   // k split
  const int arow = t >> 2, achk = t & 3;

  f32x4 acc[8];
#pragma unroll
  for (int b = 0; b < 8; ++b) acc[b] = (f32x4)0.f;

  for (int s = 0; s < 16; ++s) {
    int kb = k0 + s * 32;
    __syncthreads();
    gld16(&lb[t * 8],        &BT[(size_t)arow * N_NODES + kb + achk * 8]);
    gld16(&lb[2048 + t * 8], &BT[(size_t)(64 + arow) * N_NODES + kb + achk * 8]);
    const float* ap = &Wup[(size_t)(r0 + (t >> 2)) * N_NODES + kb + (t & 3) * 8];
    float4 v0 = *(const float4*)ap;
    float4 v1 = *(const float4*)(ap + 4);
    ushort4 o0, o1;
    o0.x = f2bf(v0.x); o0.y = f2bf(v0.y); o0.z = f2bf(v0.z); o0.w = f2bf(v0.w);
    o1.x = f2bf(v1.x); o1.y = f2bf(v1.y); o1.z = f2bf(v1.z); o1.w = f2bf(v1.w);
    *(ushort4*)&la[t * 8] = o0;
    *(ushort4*)&la[t * 8 + 4] = o1;
    __syncthreads();                                 // drains vm+lgkm: tiles visible

    bf16x8 a0 = *(const bf16x8*)&la[(w * 16 + l15) * 32 + q * 8];
#pragma unroll
    for (int nt = 0; nt < 8; ++nt) {
      bf16x8 b = *(const bf16x8*)&lb[(nt * 16 + l15) * 32 + q * 8];
      acc[nt] = __builtin_amdgcn_mfma_f32_16x16x32_bf16(a0, b, acc[nt], 0, 0, 0);
    }
  }
  float* ct = accBase + (size_t)blockIdx.y * SLICE_ELEMS + (size_t)blockIdx.x * 8192;
#pragma unroll
  for (int nt = 0; nt < 8; ++nt)
    *(f32x4*)&ct[((w * 8 + nt) * 256) + (q * 16 + l15) * 4] = acc[nt];
}

// sum packed partials + epilogue -> bf16 row-major
// mode 0 (upsample, 64-row tiles): slot=w*8+nt, row=tile*64+w*16+q*4+i, col=nt*16+l15
// mode 1 (agg128, 128-row tiles): slot=w*16+mt*8+nt, row=tile*128+w*32+mt*16+q*4+i,
//                                 col=nt*16+l15;  v=relu(rsqrt(deg)*s+bias_col)
__global__ void reduce64_kernel(const float* __restrict__ acc,
                                unsigned short* __restrict__ dst,
                                const float* __restrict__ bias_row,
                                const float* __restrict__ bias_col,
                                const float* __restrict__ deg, int mode, int nSlices) {
  int p = blockIdx.x * 256 + threadIdx.x;
  float s = 0.f;
  for (int sp = 0; sp < nSlices; ++sp) s += acc[(size_t)sp * SLICE_ELEMS + p];
  int row, col;
  float v;
  if (mode == 0) {
    int tile = p >> 13, r = p & 8191;
    int grp = r >> 8;
    int w = grp >> 3, nt = grp & 7;
    int r2 = r & 255;
    int i = r2 & 3, ql = r2 >> 2;
    row = tile * 64 + w * 16 + (ql >> 4) * 4 + i;
    col = nt * 16 + (ql & 15);
    v = s + bias_row[row];
  } else {
    int tile = p >> 14, r = p & 16383;
    int grp = r >> 8;                                // w*16+mt*8+nt, 0..63
    int w = grp >> 4, mt = (grp >> 3) & 1, nt = grp & 7;
    int r2 = r & 255;
    int i = r2 & 3, ql = r2 >> 2;
    row = tile * 128 + w * 32 + mt * 16 + (ql >> 4) * 4 + i;
    col = nt * 16 + (ql & 15);
    float d = deg[row];
    float dv = d > 0.f ? rsqrtf(d) : 0.f;
    v = fmaxf(dv * s + bias_col[col], 0.f);
  }
  dst[(size_t)row * DIM + col] = f2bf(v);
}

// ---------------- TRIANGULAR rebuild: S = sigmoid(XA @ XB^T), K=128, S symmetric ----------
// (unchanged from R10; staging T2-swizzled; bitwise-identical mirrored tiles)

template <int MODE>
__global__ __launch_bounds__(256)
void rebuild_kernel(const unsigned short* __restrict__ XA,
                    const unsigned short* __restrict__ XB,
                    void* __restrict__ out, long p1 /*MODE0:row0, MODE1:ldo*/,
                    long col0, float* __restrict__ deg, int nB) {
  __shared__ __align__(16) unsigned short smem[34816];   // 69.6KB: staging 64KB / lC+lCt
  __shared__ float lcol[128];
  __shared__ float lrow[128];
  unsigned short* lA = smem;
  unsigned short* lB = smem + 16384;
  const int t = threadIdx.x, w = t >> 6, lane = t & 63;
  const int q = lane >> 4, l15 = lane & 15;
  const int sx = (l15 >> 1) & 3;                     // read-side swizzle key

  int rem = blockIdx.x, bi = 0;
  while (rem >= nB - bi) { rem -= nB - bi; ++bi; }
  const int bj = bi + rem;
  const int i0 = bi * 128, j0 = bj * 128;
  const bool offdiag = (bi != bj);

  const int srow = t >> 2;
  const int xchk = (t & 3) ^ ((t >> 3) & 3);         // source chunk (pre-swizzled)
#pragma unroll
  for (int kk = 0; kk < 4; ++kk)
#pragma unroll
    for (int h = 0; h < 2; ++h) {
      gld16(&lA[kk * 4096 + h * 2048 + t * 8],
            &XA[(size_t)(i0 + h * 64 + srow) * DIM + kk * 32 + xchk * 8]);
      gld16(&lB[kk * 4096 + h * 2048 + t * 8],
            &XB[(size_t)(j0 + h * 64 + srow) * DIM + kk * 32 + xchk * 8]);
    }
  if (MODE == 0 && t < 128) { lcol[t] = 0.f; lrow[t] = 0.f; }
  __syncthreads();

  f32x4 acc[2][8];
#pragma unroll
  for (int a = 0; a < 2; ++a)
#pragma unroll
    for (int b = 0; b < 8; ++b) acc[a][b] = (f32x4)0.f;

#pragma unroll
  for (int kk = 0; kk < 4; ++kk) {
    bf16x8 a0 = *(const bf16x8*)&lA[kk * 4096 + (w * 32 + l15) * 32 + ((q ^ sx)) * 8];
    bf16x8 a1 = *(const bf16x8*)&lA[kk * 4096 + (w * 32 + 16 + l15) * 32 + ((q ^ sx)) * 8];
#pragma unroll
    for (int nt = 0; nt < 8; ++nt) {
      bf16x8 b = *(const bf16x8*)&lB[kk * 4096 + (nt * 16 + l15) * 32 + ((q ^ sx)) * 8];
      acc[0][nt] = __builtin_amdgcn_mfma_f32_16x16x32_bf16(a0, b, acc[0][nt], 0, 0, 0);
      acc[1][nt] = __builtin_amdgcn_mfma_f32_16x16x32_bf16(a1, b, acc[1][nt], 0, 0, 0);
    }
  }
  __syncthreads();   // staging reads done; smem reusable

  if (MODE == 0) {
    unsigned short* lC  = smem;          // [128][136] bf16
    unsigned short* lCt = smem + 17408;  // [128][136] bf16 (transposed tile)
    float rs[2][4] = {{0.f, 0.f, 0.f, 0.f}, {0.f, 0.f, 0.f, 0.f}};
#pragma unroll
    for (int mt = 0; mt < 2; ++mt)
#pragma unroll
      for (int nt = 0; nt < 8; ++nt) {
        float cs = 0.f;
#pragma unroll
        for (int i = 0; i < 4; ++i) {
          float sv = sigmoidf_(acc[mt][nt][i]);
          cs += sv;
          unsigned short hb = f2bf(sv);
          int row = w * 32 + mt * 16 + q * 4 + i, colL = nt * 16 + l15;
          lC[row * 136 + colL] = hb;
          if (offdiag) { lCt[colL * 136 + row] = hb; rs[mt][i] += sv; }
        }
        cs += __shfl_xor(cs, 16);
        cs += __shfl_xor(cs, 32);
        if (lane < 16) atomicAdd(&lcol[nt * 16 + lane], cs);
      }
    if (offdiag) {
#pragma unroll
      for (int mt = 0; mt < 2; ++mt)
#pragma unroll
        for (int i = 0; i < 4; ++i) {
          float v = rs[mt][i];
          v += __shfl_xor(v, 1); v += __shfl_xor(v, 2);
          v += __shfl_xor(v, 4); v += __shfl_xor(v, 8);
          if (l15 == 0) atomicAdd(&lrow[w * 32 + mt * 16 + q * 4 + i], v);
        }
    }
    __syncthreads();
    unsigned short* og = (unsigned short*)out;
    {
      const long rowbase = p1 + i0, colbase = col0 + j0;
      const size_t tb = ((size_t)(rowbase >> 7) * 8 + (colbase >> 10)) * 131072;
      const int stb = (int)((colbase & 1023) >> 5);
#pragma unroll
      for (int cc = 0; cc < 8; ++cc) {
        int ch = t + cc * 256;
        int row = ch >> 4, c16 = ch & 15;
        *(bf16x8*)&og[tb + (size_t)(stb + (c16 >> 2)) * 4096 + row * 32 + (c16 & 3) * 8] =
            *(const bf16x8*)&lC[row * 136 + c16 * 8];
      }
    }
    if (offdiag) {
      const long rowbase = p1 + j0, colbase = col0 + i0;
      const size_t tb = ((size_t)(rowbase >> 7) * 8 + (colbase >> 10)) * 131072;
      const int stb = (int)((colbase & 1023) >> 5);
#pragma unroll
      for (int cc = 0; cc < 8; ++cc) {
        int ch = t + cc * 256;
        int row = ch >> 4, c16 = ch & 15;
        *(bf16x8*)&og[tb + (size_t)(stb + (c16 >> 2)) * 4096 + row * 32 + (c16 & 3) * 8] =
            *(const bf16x8*)&lCt[row * 136 + c16 * 8];
      }
    }
    if (t < 128) atomicAdd(&deg[col0 + j0 + t], lcol[t]);
    if (offdiag && t < 128) atomicAdd(&deg[col0 + i0 + t], lrow[t]);
  } else {
    float* og = (float*)out;
    float* lCf = (float*)smem;                   // [64][132] f32, stride keeps 16B align
#pragma unroll
    for (int mt = 0; mt < 2; ++mt)
#pragma unroll
      for (int nt = 0; nt < 8; ++nt)
#pragma unroll
        for (int i = 0; i < 4; ++i) acc[mt][nt][i] = sigmoidf_(acc[mt][nt][i]);
#pragma unroll
    for (int h2 = 0; h2 < 2; ++h2) {
      __syncthreads();
      if ((w >> 1) == h2) {
#pragma unroll
        for (int mt = 0; mt < 2; ++mt)
#pragma unroll
          for (int nt = 0; nt < 8; ++nt)
#pragma unroll
            for (int i = 0; i < 4; ++i)
              lCf[((w & 1) * 32 + mt * 16 + q * 4 + i) * 132 + nt * 16 + l15] =
                  acc[mt][nt][i];
      }
      __syncthreads();
#pragma unroll
      for (int j = 0; j < 8; ++j) {
        int ch = t + j * 256;
        int r64 = ch >> 5, c4 = (ch & 31) * 4;
        *(f32x4*)&og[(size_t)(i0 + h2 * 64 + r64) * p1 + j0 + c4] =
            *(const f32x4*)&lCf[r64 * 132 + c4];
      }
    }
    if (offdiag) {
#pragma unroll
      for (int h2 = 0; h2 < 2; ++h2) {
        __syncthreads();
#pragma unroll
        for (int mt = 0; mt < 2; ++mt)
#pragma unroll
          for (int nt = 0; nt < 8; ++nt)
            if ((nt >> 2) == h2) {
#pragma unroll
              for (int i = 0; i < 4; ++i)
                lCf[((nt & 3) * 16 + l15) * 132 + (w * 32 + mt * 16 + q * 4 + i)] =
                    acc[mt][nt][i];
            }
        __syncthreads();
#pragma unroll
        for (int j = 0; j < 8; ++j) {
          int ch = t + j * 256;
          int r64 = ch >> 5, c4 = (ch & 31) * 4;
          *(f32x4*)&og[(size_t)(j0 + h2 * 64 + r64) * p1 + i0 + c4] =
              *(const f32x4*)&lCf[r64 * 132 + c4];
        }
      }
    }
  }
}

// ---------------- Z^T = (rsqrt(deg) ⊙ (Xu @ W)) transposed, [128][8192] ----------------
// Staging T2-swizzled. zbuf (optional): zero next-gen deg buffer (folds a memset launch).

__global__ __launch_bounds__(256)
void yz_kernel(const unsigned short* __restrict__ Xu, const unsigned short* __restrict__ WT,
               const float* __restrict__ deg, unsigned short* __restrict__ ZT, int ldz,
               float* __restrict__ zbuf) {
  __shared__ __align__(16) unsigned short smem[32768];
  unsigned short* lA = smem;
  unsigned short* lB = smem + 16384;
  const int t = threadIdx.x, w = t >> 6, lane = t & 63;
  const int q = lane >> 4, l15 = lane & 15;
  const int sx = (l15 >> 1) & 3;
  const int r0 = blockIdx.x * 128;
  if (zbuf) {
    int gid = blockIdx.x * 256 + t;
    if (gid < M_NODES) zbuf[gid] = 0.f;
  }
  const int srow = t >> 2;
  const int xchk = (t & 3) ^ ((t >> 3) & 3);
#pragma unroll
  for (int kk = 0; kk < 4; ++kk)
#pragma unroll
    for (int h = 0; h < 2; ++h) {
      gld16(&lA[kk * 4096 + h * 2048 + t * 8],
            &Xu[(size_t)(r0 + h * 64 + srow) * DIM + kk * 32 + xchk * 8]);
      gld16(&lB[kk * 4096 + h * 2048 + t * 8],
            &WT[(size_t)(h * 64 + srow) * DIM + kk * 32 + xchk * 8]);
    }
  __syncthreads();

  f32x4 acc[2][8];
#pragma unroll
  for (int a = 0; a < 2; ++a)
#pragma unroll
    for (int b = 0; b < 8; ++b) acc[a][b] = (f32x4)0.f;

#pragma unroll
  for (int kk = 0; kk < 4; ++kk) {
    bf16x8 a0 = *(const bf16x8*)&lA[kk * 4096 + (w * 32 + l15) * 32 + (q ^ sx) * 8];
    bf16x8 a1 = *(const bf16x8*)&lA[kk * 4096 + (w * 32 + 16 + l15) * 32 + (q ^ sx) * 8];
#pragma unroll
    for (int nt = 0; nt < 8; ++nt) {
      bf16x8 b = *(const bf16x8*)&lB[kk * 4096 + (nt * 16 + l15) * 32 + (q ^ sx) * 8];
      acc[0][nt] = __builtin_amdgcn_mfma_f32_16x16x32_bf16(a0, b, acc[0][nt], 0, 0, 0);
      acc[1][nt] = __builtin_amdgcn_mfma_f32_16x16x32_bf16(a1, b, acc[1][nt], 0, 0, 0);
    }
  }
  __syncthreads();
  unsigned short* lT = smem;   // [c 128][r 136]
#pragma unroll
  for (int mt = 0; mt < 2; ++mt)
#pragma unroll
    for (int i = 0; i < 4; ++i) {
      int r = w * 32 + mt * 16 + q * 4 + i;
      float d = deg[r0 + r];
      float dv = d > 0.f ? rsqrtf(d) : 0.f;
#pragma unroll
      for (int nt = 0; nt < 8; ++nt)
        lT[(nt * 16 + l15) * 136 + r] = f2bf(dv * acc[mt][nt][i]);
    }
  __syncthreads();
#pragma unroll
  for (int cc = 0; cc < 8; ++cc) {
    int ch = t + cc * 256;
    int c = ch >> 4, c16 = ch & 15;
    *(bf16x8*)&ZT[(size_t)c * ldz + r0 + c16 * 8] = *(const bf16x8*)&lT[c * 136 + c16 * 8];
  }
}

// ---------------- driver ----------------

extern "C" void kernel_launch(void* const* d_in, const int* in_sizes, int n_in,
                              void* d_out, int out_size, void* d_ws, size_t ws_size,
                              hipStream_t stream) {
  (void)in_sizes; (void)n_in; (void)out_size;
  const float* X   = (const float*)d_in[0];
  const float* A   = (const float*)d_in[1];
  const float* Wup = (const float*)d_in[2];
  const float* bup = (const float*)d_in[3];
  const float* W1  = (const float*)d_in[4];
  const float* b1  = (const float*)d_in[5];
  const float* W2  = (const float*)d_in[6];
  const float* b2  = (const float*)d_in[7];

  const size_t ADJ_BYTES = (size_t)M_NODES * M_NODES * 2;
  char* ws = (char*)d_ws;
  size_t off = 0;
  auto alloc = [&](size_t bytes) {
    char* p = ws + off;
    off += (bytes + 255) & ~(size_t)255;
    return p;
  };
  float*          accb    = (float*)alloc(8 * SLICE_ELEMS * 4);                  // 33.5 MB
  unsigned short* Xu      = (unsigned short*)alloc((size_t)M_NODES * DIM * 2);
  unsigned short* ZT      = (unsigned short*)alloc((size_t)DIM * M_NODES * 2);
  unsigned short* XT      = (unsigned short*)alloc((size_t)DIM * N_NODES * 2);
  unsigned short* W1T     = (unsigned short*)alloc(DIM * DIM * 2);
  unsigned short* W2T     = (unsigned short*)alloc(DIM * DIM * 2);
  float*          colsumA = (float*)alloc(N_NODES * 4);
  float*          degA    = (float*)alloc(M_NODES * 4);
  float*          degB    = (float*)alloc(M_NODES * 4);

  unsigned short* Adj;
  if (ws_size >= off + ADJ_BYTES) Adj = (unsigned short*)(ws + off);
  else                            Adj = (unsigned short*)d_out;  // Adj dead before final write

  unsigned short* XuNew = Xu + (size_t)N_NODES * DIM;

  cast_x_kernel<<<N_NODES * DIM / 256, 256, 0, stream>>>(X, Xu, XT, colsumA);
  cast_wt2_kernel<<<128, 256, 0, stream>>>(W1, W2, W1T, W2T);

  // new = W_up @ X (+ b_up): K=4096, direct f32 A-read, 8 splits x 16 stages
  up_agg_f32<<<dim3(N_NODES / 64, 8), 256, 0, stream>>>(Wup, XT, accb);
  reduce64_kernel<<<N_NODES * DIM / 256, 256, 0, stream>>>(
      accb, XuNew, bup, nullptr, nullptr, 0, 8);

  // Adj0 blocks [[A,A],[A,.]] tiled + colsum; deg; S0 = sigmoid(new@new^T) into (4096+,4096+)
  cast_a_kernel<<<dim3(N_NODES / 256, N_NODES / 128), 256, 0, stream>>>(A, Adj, colsumA);
  init_deg_kernel<<<M_NODES / 256, 256, 0, stream>>>(colsumA, degA);
  rebuild_kernel<0><<<32 * 33 / 2, 256, 0, stream>>>(
      XuNew, XuNew, Adj, N_NODES, N_NODES, degA, 32);

  float* degCur = degA;   // deg for conv1 (prev generation's mid-loop Adj)
  float* degMid = degB;   // deg for this generation's mid-loop Adj
  for (int it = 0; it < 3; ++it) {
    // conv1 (Adj = prev mid-loop matrix; iter0: Adj0). yz also zeroes degMid.
    yz_kernel<<<M_NODES / 128, 256, 0, stream>>>(Xu, W1T, degCur, ZT, M_NODES, degMid);
    agg128_kernel<<<dim3(M_NODES / 128, 8), 256, 0, stream>>>(Adj, ZT, M_NODES, accb, 16);
    reduce64_kernel<<<M_NODES * DIM / 256, 256, 0, stream>>>(
        accb, Xu, nullptr, b1, degCur, 1, 8);
    // mid-loop Adj rebuild (triangular) + deg into degMid
    rebuild_kernel<0><<<64 * 65 / 2, 256, 0, stream>>>(
        Xu, Xu, Adj, 0, 0, degMid, 64);
    // conv2 (Adj = mid-loop matrix)
    yz_kernel<<<M_NODES / 128, 256, 0, stream>>>(Xu, W2T, degMid, ZT, M_NODES, nullptr);
    agg128_kernel<<<dim3(M_NODES / 128, 8), 256, 0, stream>>>(Adj, ZT, M_NODES, accb, 16);
    reduce64_kernel<<<M_NODES * DIM / 256, 256, 0, stream>>>(
        accb, Xu, nullptr, b2, degMid, 1, 8);
    if (it == 2)
      rebuild_kernel<1><<<64 * 65 / 2, 256, 0, stream>>>(
          Xu, Xu, d_out, M_NODES, 0, nullptr, 64);
    float* tmp = degCur; degCur = degMid; degMid = tmp;
  }
}